// Round 2
// baseline (755.169 us; speedup 1.0000x reference)
//
#include <hip/hip_runtime.h>
#include <hip/hip_bf16.h>
#include <cstdint>
#include <cmath>

// Self-attention, B=8 T=1024 H=8 D=512 (hidden 4096), fp32 in/out, bf16 MFMA compute.
// Per-batch pipeline to keep workspace ~136 MB (prev 408 MB version crashed — OOB scratch suspected).
//
//   1) convert x, Wq*s, Wk*s, Wv, Wo to bf16   (s = 512^-0.25 folded into weights)
//   per batch b:
//     2) QKVb = xb[b] @ Wqkv^T            [1024 x 12288] bf16
//     3) Vtb  = transpose of V part       [8][512][1024] bf16
//     4) Sb   = Q @ K^T per head          [8][1024][1024] bf16 (causal upper tiles skipped)
//     5) causal softmax rows in place
//     6) AO[b] = P @ Vtb^T per head       -> AO_all [8192 x 4096] bf16
//   7) out = AO_all @ Wo^T                fp32 -> d_out

typedef __attribute__((ext_vector_type(8))) short short8;
typedef __attribute__((ext_vector_type(4))) float f32x4;

#define DEVINL __device__ __forceinline__

DEVINL float bf2f(ushort u) { union { uint32_t i; float f; } w; w.i = (uint32_t)u << 16; return w.f; }
DEVINL ushort f2bf(float f) {
  union { float f; uint32_t i; } w; w.f = f;
  uint32_t r = w.i + 0x7FFFu + ((w.i >> 16) & 1u);   // RNE
  return (ushort)(r >> 16);
}

DEVINL void gl_lds16(const ushort* g, ushort* l) {
  __builtin_amdgcn_global_load_lds(
      (const __attribute__((address_space(1))) uint32_t*)g,
      (__attribute__((address_space(3))) uint32_t*)l, 16, 0, 0);
}

// ---------------- fp32 -> bf16 convert (8 elems/thread), optional scale ----------------
__global__ __launch_bounds__(256) void cvt_f32_bf16(const float* __restrict__ in,
                                                    ushort* __restrict__ out,
                                                    int n8, float scale) {
  int i = blockIdx.x * 256 + threadIdx.x;
  if (i >= n8) return;
  const float4* p = (const float4*)in + (size_t)i * 2;
  float4 a = p[0], b = p[1];
  short8 o;
  o[0] = (short)f2bf(a.x * scale); o[1] = (short)f2bf(a.y * scale);
  o[2] = (short)f2bf(a.z * scale); o[3] = (short)f2bf(a.w * scale);
  o[4] = (short)f2bf(b.x * scale); o[5] = (short)f2bf(b.y * scale);
  o[6] = (short)f2bf(b.z * scale); o[7] = (short)f2bf(b.w * scale);
  ((short8*)out)[i] = o;
}

// ---------------- generic bf16 C = A * B^T GEMM, m97 structure ----------------
// 128x128 tile, BK=32, 4 waves (2x2 of 64x64), 16x16x32 MFMA.
// A: [M,K] row-major (lda), B: [N,K] row-major (ldb). blockIdx.z = head (strides *h).
// CSKIP: skip blocks entirely above causal diagonal (for QK^T).
// CKB:   limit K loop to <= (bm+1)*128 (for PV; P is zero beyond, unread).
// OUTF32: 1 -> fp32 C, 0 -> bf16 C.
template<bool CSKIP, bool CKB, int OUTF32>
__global__ __launch_bounds__(256) void gemm_bt(
    const ushort* __restrict__ A0, long long sAh,
    const ushort* __restrict__ B0, long long sBh,
    void* __restrict__ C0, long long sCh,
    int lda, int ldb, int ldc, int K)
{
  const int bm = blockIdx.x, bn = blockIdx.y, hi = blockIdx.z;
  if (CSKIP && bn > bm) return;
  const ushort* A = A0 + (size_t)hi * sAh;
  const ushort* B = B0 + (size_t)hi * sBh;
  int kend = K;
  if (CKB) { int kb = (bm + 1) * 128; kend = kb < K ? kb : K; }

  __shared__ ushort As[128 * 32];
  __shared__ ushort Bs[128 * 32];

  const int tid = threadIdx.x;
  const int wave = tid >> 6, lane = tid & 63;
  const int wr = wave >> 1, wc = wave & 1;
  const int l15 = lane & 15, kq = lane >> 4;

  // staging: each wave covers 16 rows (1 KB) per issue; 2 issues cover 128 rows per tile
  const ushort* ag = A + (size_t)(bm * 128 + wave * 16 + (lane >> 2)) * lda + (lane & 3) * 8;
  const ushort* bg = B + (size_t)(bn * 128 + wave * 16 + (lane >> 2)) * ldb + (lane & 3) * 8;
  ushort* al = &As[wave * 16 * 32];   // wave-uniform LDS dest (HW: base + lane*16)
  ushort* bl = &Bs[wave * 16 * 32];
  const size_t aoff = (size_t)64 * lda, boff = (size_t)64 * ldb;

  f32x4 acc[4][4] = {};

  for (int kk = 0; kk < kend; kk += 32) {
    gl_lds16(ag + kk, al);
    gl_lds16(ag + kk + aoff, al + 64 * 32);
    gl_lds16(bg + kk, bl);
    gl_lds16(bg + kk + boff, bl + 64 * 32);
    __syncthreads();   // compiler emits vmcnt(0) drain before barrier

    short8 af[4], bfr[4];
#pragma unroll
    for (int m = 0; m < 4; ++m)
      af[m] = *(const short8*)&As[(wr * 64 + m * 16 + l15) * 32 + kq * 8];
#pragma unroll
    for (int n = 0; n < 4; ++n)
      bfr[n] = *(const short8*)&Bs[(wc * 64 + n * 16 + l15) * 32 + kq * 8];
#pragma unroll
    for (int m = 0; m < 4; ++m)
#pragma unroll
      for (int n = 0; n < 4; ++n)
        acc[m][n] = __builtin_amdgcn_mfma_f32_16x16x32_bf16(af[m], bfr[n], acc[m][n], 0, 0, 0);
    __syncthreads();
  }

  // C fragment layout (m89-verified): col = lane&15, row = (lane>>4)*4 + reg
  const int r0 = bm * 128 + wr * 64 + (lane >> 4) * 4;
  const int c0 = bn * 128 + wc * 64 + l15;
  if constexpr (OUTF32 == 1) {
    float* C = (float*)C0 + (size_t)hi * sCh;
#pragma unroll
    for (int m = 0; m < 4; ++m)
#pragma unroll
      for (int n = 0; n < 4; ++n)
#pragma unroll
        for (int r = 0; r < 4; ++r)
          C[(size_t)(r0 + m * 16 + r) * ldc + (c0 + n * 16)] = acc[m][n][r];
  } else {
    ushort* C = (ushort*)C0 + (size_t)hi * sCh;
#pragma unroll
    for (int m = 0; m < 4; ++m)
#pragma unroll
      for (int n = 0; n < 4; ++n)
#pragma unroll
        for (int r = 0; r < 4; ++r)
          C[(size_t)(r0 + m * 16 + r) * ldc + (c0 + n * 16)] = f2bf(acc[m][n][r]);
  }
}

// ---------------- V transpose (per batch): QKVb[s][8192+h*512+d] -> Vtb[h][d][s] ----------------
__global__ __launch_bounds__(256) void transposeV(const ushort* __restrict__ QKVb,
                                                  ushort* __restrict__ Vtb) {
  __shared__ ushort tile[64][72];     // +8 pad breaks bank conflicts
  const int bx = blockIdx.x;          // s-tile (16)
  const int by = blockIdx.y;          // d-tile (8)
  const int h  = blockIdx.z;          // head (8)
  const int t = threadIdx.x;
  const int r = t >> 2, c = (t & 3) * 16;

  const ushort* src = QKVb + (size_t)(bx * 64 + r) * 12288 + 8192 + h * 512 + by * 64 + c;
  short8 v0 = *(const short8*)src;
  short8 v1 = *(const short8*)(src + 8);
#pragma unroll
  for (int j = 0; j < 8; ++j) { tile[r][c + j] = (ushort)v0[j]; tile[r][c + 8 + j] = (ushort)v1[j]; }
  __syncthreads();

  ushort* dst = Vtb + (size_t)(h * 512 + by * 64 + r) * 1024 + bx * 64 + c;
  short8 o0, o1;
#pragma unroll
  for (int j = 0; j < 8; ++j) { o0[j] = (short)tile[c + j][r]; o1[j] = (short)tile[c + 8 + j][r]; }
  *(short8*)dst = o0;
  *(short8*)(dst + 8) = o1;
}

// ---------------- causal softmax, one wave per row, in place on bf16 Sb [8][1024][1024] ----------------
__global__ __launch_bounds__(256) void softmax_causal(ushort* __restrict__ S) {
  const int wave = threadIdx.x >> 6, lane = threadIdx.x & 63;
  const size_t row_id = (size_t)blockIdx.x * 4 + wave;   // 0..8191
  const int t = (int)(row_id & 1023);
  ushort* row = S + row_id * 1024;
  const int j0 = lane * 16;

  short8 v0 = *(const short8*)&row[j0];
  short8 v1 = *(const short8*)&row[j0 + 8];
  float f[16];
#pragma unroll
  for (int i = 0; i < 8; ++i) { f[i] = bf2f((ushort)v0[i]); f[8 + i] = bf2f((ushort)v1[i]); }

  float m = -1e30f;
#pragma unroll
  for (int i = 0; i < 16; ++i) {
    if (j0 + i > t) f[i] = -1e30f;    // causal mask (also covers garbage in skipped tiles)
    m = fmaxf(m, f[i]);
  }
#pragma unroll
  for (int off = 32; off; off >>= 1) m = fmaxf(m, __shfl_xor(m, off));

  float s = 0.f;
#pragma unroll
  for (int i = 0; i < 16; ++i) { f[i] = __expf(f[i] - m); s += f[i]; }
#pragma unroll
  for (int off = 32; off; off >>= 1) s += __shfl_xor(s, off);
  const float inv = 1.f / s;

#pragma unroll
  for (int i = 0; i < 8; ++i) {
    v0[i] = (short)f2bf(f[i] * inv);
    v1[i] = (short)f2bf(f[8 + i] * inv);
  }
  *(short8*)&row[j0] = v0;
  *(short8*)&row[j0 + 8] = v1;
}

// ---------------- launch ----------------
extern "C" void kernel_launch(void* const* d_in, const int* in_sizes, int n_in,
                              void* d_out, int out_size, void* d_ws, size_t ws_size,
                              hipStream_t stream) {
  const float* x  = (const float*)d_in[0];
  const float* Wq = (const float*)d_in[1];
  const float* Wk = (const float*)d_in[2];
  const float* Wv = (const float*)d_in[3];
  const float* Wo = (const float*)d_in[4];
  float* out = (float*)d_out;

  // workspace layout (ushort elements), total ~136 MiB
  ushort* xb   = (ushort*)d_ws;                 //  8192*512   = 4,194,304
  ushort* Wqkv = xb   + (size_t)4194304;        // 12288*512   = 6,291,456
  ushort* Wob  = Wqkv + (size_t)6291456;        //   512*4096  = 2,097,152
  ushort* AO   = Wob  + (size_t)2097152;        //  8192*4096  = 33,554,432
  ushort* QKVb = AO   + (size_t)33554432;       //  1024*12288 = 12,582,912
  ushort* Vtb  = QKVb + (size_t)12582912;       //  8*512*1024 = 4,194,304
  ushort* Sb   = Vtb  + (size_t)4194304;        //  8*1024*1024= 8,388,608
  // end = 71,303,168 ushorts = 142,606,336 bytes

  const float iscale = (float)(1.0 / pow(512.0, 0.25));   // folded into Wq, Wk

  cvt_f32_bf16<<<2048, 256, 0, stream>>>(x,  xb,             524288, 1.0f);
  cvt_f32_bf16<<<1024, 256, 0, stream>>>(Wq, Wqkv,           262144, iscale);
  cvt_f32_bf16<<<1024, 256, 0, stream>>>(Wk, Wqkv + 2097152, 262144, iscale);
  cvt_f32_bf16<<<1024, 256, 0, stream>>>(Wv, Wqkv + 4194304, 262144, 1.0f);
  cvt_f32_bf16<<<1024, 256, 0, stream>>>(Wo, Wob,            262144, 1.0f);

  for (int b = 0; b < 8; ++b) {
    // QKVb = x[b] @ Wqkv^T : [1024 x 12288]
    gemm_bt<false, false, 0><<<dim3(8, 96, 1), 256, 0, stream>>>(
        xb + (size_t)b * 524288, 0, Wqkv, 0, QKVb, 0, 512, 512, 12288, 512);

    // V transpose -> Vtb[h][d][s]
    transposeV<<<dim3(16, 8, 8), 256, 0, stream>>>(QKVb, Vtb);

    // Sb = Q @ K^T per head; causal block skip
    gemm_bt<true, false, 0><<<dim3(8, 8, 8), 256, 0, stream>>>(
        QKVb,        512LL,
        QKVb + 4096, 512LL,
        Sb,          1048576LL,
        12288, 12288, 1024, 512);

    // causal softmax in place (8192 rows)
    softmax_causal<<<2048, 256, 0, stream>>>(Sb);

    // AO[b] = P @ Vtb^T per head, causal K bound
    gemm_bt<false, true, 0><<<dim3(8, 4, 8), 256, 0, stream>>>(
        Sb,  1048576LL,
        Vtb, 524288LL,
        AO + (size_t)b * 4194304, 512LL,
        1024, 1024, 4096, 1024);
  }

  // out = AO @ Wo^T, fp32 [8192 x 512]
  gemm_bt<false, false, 1><<<dim3(64, 4, 1), 256, 0, stream>>>(
      AO, 0, Wob, 0, out, 0, 4096, 4096, 512, 4096);
}

// Round 4
// 626.308 us; speedup vs baseline: 1.2057x; 1.2057x over previous
//
#include <hip/hip_runtime.h>
#include <hip/hip_bf16.h>
#include <cstdint>
#include <cmath>

// Self-attention, B=8 T=1024 H=8 D=512 (hidden 4096), fp32 in/out, bf16 MFMA compute.
// Group-adaptive pipeline: batches processed in groups of g in {4,2,1}, chosen as the
// largest whose workspace requirement fits ws_size (R(1)=142.6MB is the known-good floor).
//
//   1) convert x, Wq*s, Wk*s, Wv, Wo to bf16   (s = 512^-0.25 folded into weights)
//   per group grp (ng = 8/g iterations):
//     2) QKVg = x[grp] @ Wqkv^T           [g*1024 x 12288] bf16
//     3) Vtg  = transpose of V part       [g*8][512][1024] bf16
//     4) Sg   = Q @ K^T per (b,h)         [g*8][1024][1024] bf16 (causal upper tiles skipped)
//     5) causal softmax rows in place
//     6) AO[grp] = P @ Vtg^T per (b,h)    -> AO [8192 x 4096] bf16
//   7) out = AO @ Wo^T, K split x4 with fp32 atomicAdd (out zeroed first)

typedef __attribute__((ext_vector_type(8))) short short8;
typedef __attribute__((ext_vector_type(4))) float f32x4;

#define DEVINL __device__ __forceinline__

DEVINL float bf2f(ushort u) { union { uint32_t i; float f; } w; w.i = (uint32_t)u << 16; return w.f; }
DEVINL ushort f2bf(float f) {
  union { float f; uint32_t i; } w; w.f = f;
  uint32_t r = w.i + 0x7FFFu + ((w.i >> 16) & 1u);   // RNE
  return (ushort)(r >> 16);
}

DEVINL void gl_lds16(const ushort* g, ushort* l) {
  __builtin_amdgcn_global_load_lds(
      (const __attribute__((address_space(1))) uint32_t*)g,
      (__attribute__((address_space(3))) uint32_t*)l, 16, 0, 0);
}

// ---------------- fp32 -> bf16 convert (8 elems/thread), optional scale ----------------
__global__ __launch_bounds__(256) void cvt_f32_bf16(const float* __restrict__ in,
                                                    ushort* __restrict__ out,
                                                    int n8, float scale) {
  int i = blockIdx.x * 256 + threadIdx.x;
  if (i >= n8) return;
  const float4* p = (const float4*)in + (size_t)i * 2;
  float4 a = p[0], b = p[1];
  short8 o;
  o[0] = (short)f2bf(a.x * scale); o[1] = (short)f2bf(a.y * scale);
  o[2] = (short)f2bf(a.z * scale); o[3] = (short)f2bf(a.w * scale);
  o[4] = (short)f2bf(b.x * scale); o[5] = (short)f2bf(b.y * scale);
  o[6] = (short)f2bf(b.z * scale); o[7] = (short)f2bf(b.w * scale);
  ((short8*)out)[i] = o;
}

// ---------------- zero fp32 buffer ----------------
__global__ __launch_bounds__(256) void zerof4(float4* __restrict__ p, int n4) {
  int i = blockIdx.x * 256 + threadIdx.x;
  if (i < n4) p[i] = float4{0.f, 0.f, 0.f, 0.f};
}

// ---------------- generic bf16 C = A * B^T GEMM, m97 structure ----------------
// 128x128 tile, BK=32, 4 waves (2x2 of 64x64), 16x16x32 MFMA.
// A: [M,K] row-major (lda), B: [N,K] row-major (ldb).
// ZBH: blockIdx.z -> (bi=z>>3)*s?b + (hi=z&7)*s?h ; else offset = z*s?h.
// CSKIP: skip blocks above causal diagonal (QK^T). CKB: K limited to (bm+1)*128 (PV).
// EPI: 0 = bf16 store, 1 = f32 store, 2 = f32 atomicAdd (K-split accumulate).
template<bool CSKIP, bool CKB, int EPI, bool ZBH>
__global__ __launch_bounds__(256) void gemm_bt(
    const ushort* __restrict__ A0, long long sAb, long long sAh,
    const ushort* __restrict__ B0, long long sBb, long long sBh,
    void* __restrict__ C0, long long sCb, long long sCh,
    int lda, int ldb, int ldc, int K)
{
  const int bm = blockIdx.x, bn = blockIdx.y, bz = blockIdx.z;
  if (CSKIP && bn > bm) return;
  long long za, zb, zc;
  if (ZBH) {
    const long long bi = bz >> 3, hi = bz & 7;
    za = bi * sAb + hi * sAh; zb = bi * sBb + hi * sBh; zc = bi * sCb + hi * sCh;
  } else {
    za = (long long)bz * sAh; zb = (long long)bz * sBh; zc = (long long)bz * sCh;
  }
  const ushort* A = A0 + za;
  const ushort* B = B0 + zb;
  int kend = K;
  if (CKB) { int kb = (bm + 1) * 128; kend = kb < K ? kb : K; }

  __shared__ ushort As[128 * 32];
  __shared__ ushort Bs[128 * 32];

  const int tid = threadIdx.x;
  const int wave = tid >> 6, lane = tid & 63;
  const int wr = wave >> 1, wc = wave & 1;
  const int l15 = lane & 15, kq = lane >> 4;

  // staging: each wave covers 16 rows (1 KB) per issue; 2 issues cover 128 rows per tile
  const ushort* ag = A + (size_t)(bm * 128 + wave * 16 + (lane >> 2)) * lda + (lane & 3) * 8;
  const ushort* bg = B + (size_t)(bn * 128 + wave * 16 + (lane >> 2)) * ldb + (lane & 3) * 8;
  ushort* al = &As[wave * 16 * 32];   // wave-uniform LDS dest (HW: base + lane*16)
  ushort* bl = &Bs[wave * 16 * 32];
  const size_t aoff = (size_t)64 * lda, boff = (size_t)64 * ldb;

  f32x4 acc[4][4] = {};

  for (int kk = 0; kk < kend; kk += 32) {
    gl_lds16(ag + kk, al);
    gl_lds16(ag + kk + aoff, al + 64 * 32);
    gl_lds16(bg + kk, bl);
    gl_lds16(bg + kk + boff, bl + 64 * 32);
    __syncthreads();   // compiler emits vmcnt(0) drain before barrier

    short8 af[4], bfr[4];
#pragma unroll
    for (int m = 0; m < 4; ++m)
      af[m] = *(const short8*)&As[(wr * 64 + m * 16 + l15) * 32 + kq * 8];
#pragma unroll
    for (int n = 0; n < 4; ++n)
      bfr[n] = *(const short8*)&Bs[(wc * 64 + n * 16 + l15) * 32 + kq * 8];
#pragma unroll
    for (int m = 0; m < 4; ++m)
#pragma unroll
      for (int n = 0; n < 4; ++n)
        acc[m][n] = __builtin_amdgcn_mfma_f32_16x16x32_bf16(af[m], bfr[n], acc[m][n], 0, 0, 0);
    __syncthreads();
  }

  // C fragment layout (m89-verified): col = lane&15, row = (lane>>4)*4 + reg
  const int r0 = bm * 128 + wr * 64 + (lane >> 4) * 4;
  const int c0 = bn * 128 + wc * 64 + l15;
  if constexpr (EPI == 0) {
    ushort* C = (ushort*)C0 + zc;
#pragma unroll
    for (int m = 0; m < 4; ++m)
#pragma unroll
      for (int n = 0; n < 4; ++n)
#pragma unroll
        for (int r = 0; r < 4; ++r)
          C[(size_t)(r0 + m * 16 + r) * ldc + (c0 + n * 16)] = f2bf(acc[m][n][r]);
  } else if constexpr (EPI == 1) {
    float* C = (float*)C0 + zc;
#pragma unroll
    for (int m = 0; m < 4; ++m)
#pragma unroll
      for (int n = 0; n < 4; ++n)
#pragma unroll
        for (int r = 0; r < 4; ++r)
          C[(size_t)(r0 + m * 16 + r) * ldc + (c0 + n * 16)] = acc[m][n][r];
  } else {
    float* C = (float*)C0 + zc;
#pragma unroll
    for (int m = 0; m < 4; ++m)
#pragma unroll
      for (int n = 0; n < 4; ++n)
#pragma unroll
        for (int r = 0; r < 4; ++r)
          atomicAdd(&C[(size_t)(r0 + m * 16 + r) * ldc + (c0 + n * 16)], acc[m][n][r]);
  }
}

// ---------------- V transpose: QKVg[b_local*1024+s][8192+h*512+d] -> Vtg[bh][d][s] ----------------
__global__ __launch_bounds__(256) void transposeV(const ushort* __restrict__ QKVg,
                                                  ushort* __restrict__ Vtg) {
  __shared__ ushort tile[64][72];     // +8 pad breaks bank conflicts
  const int bx = blockIdx.x;          // s-tile (16)
  const int by = blockIdx.y;          // d-tile (8)
  const int bz = blockIdx.z;          // local bh (8g)
  const int b = bz >> 3, h = bz & 7;
  const int t = threadIdx.x;
  const int r = t >> 2, c = (t & 3) * 16;

  const ushort* src = QKVg + (size_t)(b * 1024 + bx * 64 + r) * 12288 + 8192 + h * 512 + by * 64 + c;
  short8 v0 = *(const short8*)src;
  short8 v1 = *(const short8*)(src + 8);
#pragma unroll
  for (int j = 0; j < 8; ++j) { tile[r][c + j] = (ushort)v0[j]; tile[r][c + 8 + j] = (ushort)v1[j]; }
  __syncthreads();

  ushort* dst = Vtg + (size_t)(bz * 512 + by * 64 + r) * 1024 + bx * 64 + c;
  short8 o0, o1;
#pragma unroll
  for (int j = 0; j < 8; ++j) { o0[j] = (short)tile[c + j][r]; o1[j] = (short)tile[c + 8 + j][r]; }
  *(short8*)dst = o0;
  *(short8*)(dst + 8) = o1;
}

// ---------------- causal softmax, one wave per row, in place on bf16 Sg ----------------
__global__ __launch_bounds__(256) void softmax_causal(ushort* __restrict__ S) {
  const int wave = threadIdx.x >> 6, lane = threadIdx.x & 63;
  const size_t row_id = (size_t)blockIdx.x * 4 + wave;
  const int t = (int)(row_id & 1023);
  ushort* row = S + row_id * 1024;
  const int j0 = lane * 16;

  short8 v0 = *(const short8*)&row[j0];
  short8 v1 = *(const short8*)&row[j0 + 8];
  float f[16];
#pragma unroll
  for (int i = 0; i < 8; ++i) { f[i] = bf2f((ushort)v0[i]); f[8 + i] = bf2f((ushort)v1[i]); }

  float m = -1e30f;
#pragma unroll
  for (int i = 0; i < 16; ++i) {
    if (j0 + i > t) f[i] = -1e30f;    // causal mask (also covers garbage in skipped tiles)
    m = fmaxf(m, f[i]);
  }
#pragma unroll
  for (int off = 32; off; off >>= 1) m = fmaxf(m, __shfl_xor(m, off));

  float s = 0.f;
#pragma unroll
  for (int i = 0; i < 16; ++i) { f[i] = __expf(f[i] - m); s += f[i]; }
#pragma unroll
  for (int off = 32; off; off >>= 1) s += __shfl_xor(s, off);
  const float inv = 1.f / s;

#pragma unroll
  for (int i = 0; i < 8; ++i) {
    v0[i] = (short)f2bf(f[i] * inv);
    v1[i] = (short)f2bf(f[8 + i] * inv);
  }
  *(short8*)&row[j0] = v0;
  *(short8*)&row[j0 + 8] = v1;
}

// ---------------- launch ----------------
extern "C" void kernel_launch(void* const* d_in, const int* in_sizes, int n_in,
                              void* d_out, int out_size, void* d_ws, size_t ws_size,
                              hipStream_t stream) {
  const float* x  = (const float*)d_in[0];
  const float* Wq = (const float*)d_in[1];
  const float* Wk = (const float*)d_in[2];
  const float* Wv = (const float*)d_in[3];
  const float* Wo = (const float*)d_in[4];
  float* out = (float*)d_out;

  // group size: largest g whose layout fits ws_size. R(g) = 92,274,688 + g*50,331,648 bytes.
  const int g = (ws_size >= 293601280ull) ? 4 : (ws_size >= 192937984ull) ? 2 : 1;
  const int ng = 8 / g;

  // workspace layout (ushort elements)
  ushort* xb   = (ushort*)d_ws;                       //  8192*512     = 4,194,304
  ushort* Wqkv = xb   + (size_t)4194304;              // 12288*512     = 6,291,456
  ushort* Wob  = Wqkv + (size_t)6291456;              //   512*4096    = 2,097,152
  ushort* AO   = Wob  + (size_t)2097152;              //  8192*4096    = 33,554,432
  ushort* QKVg = AO   + (size_t)33554432;             //  g*1024*12288 = g*12,582,912
  ushort* Vtg  = QKVg + (size_t)g * 12582912;         //  g*8*512*1024 = g*4,194,304
  ushort* Sg   = Vtg  + (size_t)g * 4194304;          //  g*8*1024*1024= g*8,388,608

  const float iscale = (float)(1.0 / pow(512.0, 0.25));   // folded into Wq, Wk

  cvt_f32_bf16<<<2048, 256, 0, stream>>>(x,  xb,             524288, 1.0f);
  cvt_f32_bf16<<<1024, 256, 0, stream>>>(Wq, Wqkv,           262144, iscale);
  cvt_f32_bf16<<<1024, 256, 0, stream>>>(Wk, Wqkv + 2097152, 262144, iscale);
  cvt_f32_bf16<<<1024, 256, 0, stream>>>(Wv, Wqkv + 4194304, 262144, 1.0f);
  cvt_f32_bf16<<<1024, 256, 0, stream>>>(Wo, Wob,            262144, 1.0f);

  for (int grp = 0; grp < ng; ++grp) {
    // QKVg = x[grp] @ Wqkv^T : [g*1024 x 12288]
    gemm_bt<false, false, 0, false><<<dim3(g * 8, 96, 1), 256, 0, stream>>>(
        xb + (size_t)grp * g * 524288, 0, 0,
        Wqkv, 0, 0,
        QKVg, 0, 0,
        512, 512, 12288, 512);

    // V transpose -> Vtg[bh][d][s]
    transposeV<<<dim3(16, 8, 8 * g), 256, 0, stream>>>(QKVg, Vtg);

    // Sg = Q @ K^T per (b,h); causal block skip
    gemm_bt<true, false, 0, true><<<dim3(8, 8, 8 * g), 256, 0, stream>>>(
        QKVg,        12582912LL, 512LL,
        QKVg + 4096, 12582912LL, 512LL,
        Sg,          8388608LL,  1048576LL,
        12288, 12288, 1024, 512);

    // causal softmax in place
    softmax_causal<<<g * 2048, 256, 0, stream>>>(Sg);

    // AO[grp] = P @ Vtg^T per (b,h), causal K bound
    gemm_bt<false, true, 0, true><<<dim3(8, 4, 8 * g), 256, 0, stream>>>(
        Sg,  8388608LL, 1048576LL,
        Vtg, 4194304LL, 524288LL,
        AO + (size_t)grp * g * 4194304, 4194304LL, 512LL,
        1024, 1024, 4096, 1024);
  }

  // out = AO @ Wo^T, fp32, K split x4 with atomic accumulate
  zerof4<<<4096, 256, 0, stream>>>((float4*)out, 1048576);
  gemm_bt<false, false, 2, false><<<dim3(64, 4, 4), 256, 0, stream>>>(
      AO,  0, 1024LL,
      Wob, 0, 1024LL,
      out, 0, 0LL,
      4096, 4096, 512, 1024);
}

// Round 5
// 556.778 us; speedup vs baseline: 1.3563x; 1.1249x over previous
//
#include <hip/hip_runtime.h>
#include <hip/hip_bf16.h>
#include <cstdint>
#include <cmath>

// Self-attention, B=8 T=1024 H=8 D=512 (hidden 4096), fp32 in/out, bf16 MFMA compute.
// Group-adaptive pipeline (g in {4,2,1} by ws_size) + 2-phase double-buffered GEMM
// (counted vmcnt, raw s_barrier) + LDS-coalesced bf16 epilogue.

typedef __attribute__((ext_vector_type(8))) short short8;
typedef __attribute__((ext_vector_type(4))) float f32x4;

#define DEVINL __device__ __forceinline__

DEVINL float bf2f(ushort u) { union { uint32_t i; float f; } w; w.i = (uint32_t)u << 16; return w.f; }
DEVINL ushort f2bf(float f) {
  union { float f; uint32_t i; } w; w.f = f;
  uint32_t r = w.i + 0x7FFFu + ((w.i >> 16) & 1u);   // RNE
  return (ushort)(r >> 16);
}

DEVINL void gl_lds16(const ushort* g, ushort* l) {
  __builtin_amdgcn_global_load_lds(
      (const __attribute__((address_space(1))) uint32_t*)g,
      (__attribute__((address_space(3))) uint32_t*)l, 16, 0, 0);
}

// swizzled index into a [32 rows][128 cols] ushort staging tile (32-B-chunk XOR):
// keeps 8-ushort runs intact; spreads the 4 kq row-groups across all 32 banks.
DEVINL int csw(int row, int col) {
  return row * 128 + ((((col >> 4) ^ ((row >> 2) & 7)) << 4) | (col & 15));
}

// ---------------- fp32 -> bf16 convert (8 elems/thread), optional scale ----------------
__global__ __launch_bounds__(256) void cvt_f32_bf16(const float* __restrict__ in,
                                                    ushort* __restrict__ out,
                                                    int n8, float scale) {
  int i = blockIdx.x * 256 + threadIdx.x;
  if (i >= n8) return;
  const float4* p = (const float4*)in + (size_t)i * 2;
  float4 a = p[0], b = p[1];
  short8 o;
  o[0] = (short)f2bf(a.x * scale); o[1] = (short)f2bf(a.y * scale);
  o[2] = (short)f2bf(a.z * scale); o[3] = (short)f2bf(a.w * scale);
  o[4] = (short)f2bf(b.x * scale); o[5] = (short)f2bf(b.y * scale);
  o[6] = (short)f2bf(b.z * scale); o[7] = (short)f2bf(b.w * scale);
  ((short8*)out)[i] = o;
}

// ---------------- zero fp32 buffer ----------------
__global__ __launch_bounds__(256) void zerof4(float4* __restrict__ p, int n4) {
  int i = blockIdx.x * 256 + threadIdx.x;
  if (i < n4) p[i] = float4{0.f, 0.f, 0.f, 0.f};
}

// ---------------- bf16 C = A * B^T GEMM, 2-phase double-buffered ----------------
// 128x128 tile, BK=32, 4 waves (2x2 of 64x64), 16x16x32 MFMA.
// A: [M,K] row-major (lda), B: [N,K] row-major (ldb).
// ZBH: z -> (bi=z>>3, hi=z&7) strides; else offset = z*s?h.
// CSKIP: skip blocks above causal diagonal. CKB: K limited to (bm+1)*128.
// EPI: 0 = bf16 store (LDS-coalesced), 2 = f32 atomicAdd (K-split accumulate).
template<bool CSKIP, bool CKB, int EPI, bool ZBH>
__global__ __launch_bounds__(256) void gemm_bt(
    const ushort* __restrict__ A0, long long sAb, long long sAh,
    const ushort* __restrict__ B0, long long sBb, long long sBh,
    void* __restrict__ C0, long long sCb, long long sCh,
    int lda, int ldb, int ldc, int K)
{
  const int bm = blockIdx.x, bn = blockIdx.y, bz = blockIdx.z;
  if (CSKIP && bn > bm) return;
  long long za, zb, zc;
  if (ZBH) {
    const long long bi = bz >> 3, hi = bz & 7;
    za = bi * sAb + hi * sAh; zb = bi * sBb + hi * sBh; zc = bi * sCb + hi * sCh;
  } else {
    za = (long long)bz * sAh; zb = (long long)bz * sBh; zc = (long long)bz * sCh;
  }
  const ushort* A = A0 + za;
  const ushort* B = B0 + zb;
  int kend = K;
  if (CKB) { int kb = (bm + 1) * 128; kend = kb < K ? kb : K; }

  // [2 bufs][A 4096 | B 4096] ushorts = 32 KB; reused whole as epilogue staging.
  __shared__ ushort smem[16384];

  const int tid = threadIdx.x;
  const int wave = tid >> 6, lane = tid & 63;
  const int wr = wave >> 1, wc = wave & 1;
  const int l15 = lane & 15, kq = lane >> 4;

  const ushort* ag = A + (size_t)(bm * 128 + wave * 16 + (lane >> 2)) * lda + (lane & 3) * 8;
  const ushort* bg = B + (size_t)(bn * 128 + wave * 16 + (lane >> 2)) * ldb + (lane & 3) * 8;
  const size_t aoff = (size_t)64 * lda, boff = (size_t)64 * ldb;

  auto STAGE = [&](int buf, int kk) {
    ushort* al = &smem[buf * 8192 + wave * 16 * 32];
    ushort* bl = al + 4096;
    gl_lds16(ag + kk, al);
    gl_lds16(ag + kk + aoff, al + 64 * 32);
    gl_lds16(bg + kk, bl);
    gl_lds16(bg + kk + boff, bl + 64 * 32);
  };

  f32x4 acc[4][4] = {};
  const int nt = kend >> 5;

  STAGE(0, 0);
  for (int t = 0; t < nt; ++t) {
    const int cur = t & 1;
    if (t + 1 < nt) {
      STAGE(cur ^ 1, (t + 1) << 5);                       // next tile in flight
      asm volatile("s_waitcnt vmcnt(4)" ::: "memory");    // cur's 4 loads done; next's 4 pending
    } else {
      asm volatile("s_waitcnt vmcnt(0)" ::: "memory");    // tail: drain
    }
    __builtin_amdgcn_s_barrier();
    __builtin_amdgcn_sched_barrier(0);

    const ushort* As = &smem[cur * 8192];
    const ushort* Bs = As + 4096;
    short8 af[4], bfr[4];
#pragma unroll
    for (int m = 0; m < 4; ++m)
      af[m] = *(const short8*)&As[(wr * 64 + m * 16 + l15) * 32 + kq * 8];
#pragma unroll
    for (int n = 0; n < 4; ++n)
      bfr[n] = *(const short8*)&Bs[(wc * 64 + n * 16 + l15) * 32 + kq * 8];
#pragma unroll
    for (int m = 0; m < 4; ++m)
#pragma unroll
      for (int n = 0; n < 4; ++n)
        acc[m][n] = __builtin_amdgcn_mfma_f32_16x16x32_bf16(af[m], bfr[n], acc[m][n], 0, 0, 0);

    __builtin_amdgcn_s_barrier();                          // readers done before next STAGE overwrite
    __builtin_amdgcn_sched_barrier(0);
  }

  // C fragment layout (m89-verified): col = lane&15, row = (lane>>4)*4 + reg
  if constexpr (EPI == 0) {
    // Stage full 128x128 bf16 tile in smem (32 KB), then fully-coalesced 16-B stores.
    ushort* C = (ushort*)C0 + zc;
#pragma unroll
    for (int m = 0; m < 4; ++m)
#pragma unroll
      for (int n = 0; n < 4; ++n)
#pragma unroll
        for (int r = 0; r < 4; ++r)
          smem[csw(wr * 64 + m * 16 + kq * 4 + r, wc * 64 + n * 16 + l15)] = f2bf(acc[m][n][r]);
    __syncthreads();
    const int col = (tid & 15) * 8;
#pragma unroll
    for (int j = 0; j < 8; ++j) {
      const int rr = j * 16 + (tid >> 4);
      *(short8*)&C[(size_t)(bm * 128 + rr) * ldc + bn * 128 + col] =
          *(const short8*)&smem[csw(rr, col)];
    }
  } else {
    float* C = (float*)C0 + zc;
    const int r0 = bm * 128 + wr * 64 + (lane >> 4) * 4;
    const int c0 = bn * 128 + wc * 64 + l15;
#pragma unroll
    for (int m = 0; m < 4; ++m)
#pragma unroll
      for (int n = 0; n < 4; ++n)
#pragma unroll
        for (int r = 0; r < 4; ++r)
          atomicAdd(&C[(size_t)(r0 + m * 16 + r) * ldc + (c0 + n * 16)], acc[m][n][r]);
  }
}

// ---------------- V transpose: QKVg[b_local*1024+s][8192+h*512+d] -> Vtg[bh][d][s] ----------------
__global__ __launch_bounds__(256) void transposeV(const ushort* __restrict__ QKVg,
                                                  ushort* __restrict__ Vtg) {
  __shared__ ushort tile[64][72];     // +8 pad breaks bank conflicts
  const int bx = blockIdx.x;          // s-tile (16)
  const int by = blockIdx.y;          // d-tile (8)
  const int bz = blockIdx.z;          // local bh (8g)
  const int b = bz >> 3, h = bz & 7;
  const int t = threadIdx.x;
  const int r = t >> 2, c = (t & 3) * 16;

  const ushort* src = QKVg + (size_t)(b * 1024 + bx * 64 + r) * 12288 + 8192 + h * 512 + by * 64 + c;
  short8 v0 = *(const short8*)src;
  short8 v1 = *(const short8*)(src + 8);
#pragma unroll
  for (int j = 0; j < 8; ++j) { tile[r][c + j] = (ushort)v0[j]; tile[r][c + 8 + j] = (ushort)v1[j]; }
  __syncthreads();

  ushort* dst = Vtg + (size_t)(bz * 512 + by * 64 + r) * 1024 + bx * 64 + c;
  short8 o0, o1;
#pragma unroll
  for (int j = 0; j < 8; ++j) { o0[j] = (short)tile[c + j][r]; o1[j] = (short)tile[c + 8 + j][r]; }
  *(short8*)dst = o0;
  *(short8*)(dst + 8) = o1;
}

// ---------------- causal softmax, one wave per row, in place on bf16 Sg ----------------
__global__ __launch_bounds__(256) void softmax_causal(ushort* __restrict__ S) {
  const int wave = threadIdx.x >> 6, lane = threadIdx.x & 63;
  const size_t row_id = (size_t)blockIdx.x * 4 + wave;
  const int t = (int)(row_id & 1023);
  ushort* row = S + row_id * 1024;
  const int j0 = lane * 16;

  short8 v0 = *(const short8*)&row[j0];
  short8 v1 = *(const short8*)&row[j0 + 8];
  float f[16];
#pragma unroll
  for (int i = 0; i < 8; ++i) { f[i] = bf2f((ushort)v0[i]); f[8 + i] = bf2f((ushort)v1[i]); }

  float m = -1e30f;
#pragma unroll
  for (int i = 0; i < 16; ++i) {
    if (j0 + i > t) f[i] = -1e30f;    // causal mask (covers garbage in skipped tiles too)
    m = fmaxf(m, f[i]);
  }
#pragma unroll
  for (int off = 32; off; off >>= 1) m = fmaxf(m, __shfl_xor(m, off));

  float s = 0.f;
#pragma unroll
  for (int i = 0; i < 16; ++i) { f[i] = __expf(f[i] - m); s += f[i]; }
#pragma unroll
  for (int off = 32; off; off >>= 1) s += __shfl_xor(s, off);
  const float inv = 1.f / s;

#pragma unroll
  for (int i = 0; i < 8; ++i) {
    v0[i] = (short)f2bf(f[i] * inv);
    v1[i] = (short)f2bf(f[8 + i] * inv);
  }
  *(short8*)&row[j0] = v0;
  *(short8*)&row[j0 + 8] = v1;
}

// ---------------- launch ----------------
extern "C" void kernel_launch(void* const* d_in, const int* in_sizes, int n_in,
                              void* d_out, int out_size, void* d_ws, size_t ws_size,
                              hipStream_t stream) {
  const float* x  = (const float*)d_in[0];
  const float* Wq = (const float*)d_in[1];
  const float* Wk = (const float*)d_in[2];
  const float* Wv = (const float*)d_in[3];
  const float* Wo = (const float*)d_in[4];
  float* out = (float*)d_out;

  // group size: largest g whose layout fits ws_size. R(g) = 92,274,688 + g*50,331,648 bytes.
  const int g = (ws_size >= 293601280ull) ? 4 : (ws_size >= 192937984ull) ? 2 : 1;
  const int ng = 8 / g;

  // workspace layout (ushort elements)
  ushort* xb   = (ushort*)d_ws;                       //  8192*512     = 4,194,304
  ushort* Wqkv = xb   + (size_t)4194304;              // 12288*512     = 6,291,456
  ushort* Wob  = Wqkv + (size_t)6291456;              //   512*4096    = 2,097,152
  ushort* AO   = Wob  + (size_t)2097152;              //  8192*4096    = 33,554,432
  ushort* QKVg = AO   + (size_t)33554432;             //  g*1024*12288 = g*12,582,912
  ushort* Vtg  = QKVg + (size_t)g * 12582912;         //  g*8*512*1024 = g*4,194,304
  ushort* Sg   = Vtg  + (size_t)g * 4194304;          //  g*8*1024*1024= g*8,388,608

  const float iscale = (float)(1.0 / pow(512.0, 0.25));   // folded into Wq, Wk

  cvt_f32_bf16<<<2048, 256, 0, stream>>>(x,  xb,             524288, 1.0f);
  cvt_f32_bf16<<<1024, 256, 0, stream>>>(Wq, Wqkv,           262144, iscale);
  cvt_f32_bf16<<<1024, 256, 0, stream>>>(Wk, Wqkv + 2097152, 262144, iscale);
  cvt_f32_bf16<<<1024, 256, 0, stream>>>(Wv, Wqkv + 4194304, 262144, 1.0f);
  cvt_f32_bf16<<<1024, 256, 0, stream>>>(Wo, Wob,            262144, 1.0f);

  for (int grp = 0; grp < ng; ++grp) {
    // QKVg = x[grp] @ Wqkv^T : [g*1024 x 12288]
    gemm_bt<false, false, 0, false><<<dim3(g * 8, 96, 1), 256, 0, stream>>>(
        xb + (size_t)grp * g * 524288, 0, 0,
        Wqkv, 0, 0,
        QKVg, 0, 0,
        512, 512, 12288, 512);

    // V transpose -> Vtg[bh][d][s]
    transposeV<<<dim3(16, 8, 8 * g), 256, 0, stream>>>(QKVg, Vtg);

    // Sg = Q @ K^T per (b,h); causal block skip
    gemm_bt<true, false, 0, true><<<dim3(8, 8, 8 * g), 256, 0, stream>>>(
        QKVg,        12582912LL, 512LL,
        QKVg + 4096, 12582912LL, 512LL,
        Sg,          8388608LL,  1048576LL,
        12288, 12288, 1024, 512);

    // causal softmax in place
    softmax_causal<<<g * 2048, 256, 0, stream>>>(Sg);

    // AO[grp] = P @ Vtg^T per (b,h), causal K bound
    gemm_bt<false, true, 0, true><<<dim3(8, 4, 8 * g), 256, 0, stream>>>(
        Sg,  8388608LL, 1048576LL,
        Vtg, 4194304LL, 524288LL,
        AO + (size_t)grp * g * 4194304, 4194304LL, 512LL,
        1024, 1024, 4096, 1024);
  }

  // out = AO @ Wo^T, fp32, K split x4 with atomic accumulate
  zerof4<<<4096, 256, 0, stream>>>((float4*)out, 1048576);
  gemm_bt<false, false, 2, false><<<dim3(64, 4, 4), 256, 0, stream>>>(
      AO,  0, 1024LL,
      Wob, 0, 1024LL,
      out, 0, 0LL,
      4096, 4096, 512, 1024);
}